// Round 1
// baseline (88.200 us; speedup 1.0000x reference)
//
#include <hip/hip_runtime.h>
#include <math.h>

#define BATCH 8
#define TDIM 2048
#define DDIM 512

typedef unsigned short u16;
typedef __bf16 bf16x8 __attribute__((ext_vector_type(8)));
typedef float f32x4 __attribute__((ext_vector_type(4)));
typedef u16 u16x8 __attribute__((ext_vector_type(8)));

__device__ __forceinline__ float gelu_f(float x) {
    const float c = 0.7978845608028654f; // sqrt(2/pi)
    return 0.5f * x * (1.0f + tanhf(c * (x + 0.044715f * x * x * x)));
}

__device__ __forceinline__ u16 f2bf(float f) {
    unsigned u = __float_as_uint(f);
    return (u16)((u + 0x7FFFu + ((u >> 16) & 1u)) >> 16); // RNE, no NaN inputs
}

__device__ __forceinline__ float wave_sum(float v) {
    #pragma unroll
    for (int s = 1; s < 64; s <<= 1) v += __shfl_xor(v, s, 64);
    return v;
}

__device__ __forceinline__ void load_lds16(const void* g, void* l) {
    __builtin_amdgcn_global_load_lds(
        (const __attribute__((address_space(1))) void*)g,
        (__attribute__((address_space(3))) void*)l, 16, 0, 0);
}

// ---------------- kernel 1: norms, cos_ema, bf16 x_n ----------------
__global__ __launch_bounds__(256) void prep_kernel(
    const float* __restrict__ x, const float* __restrict__ ema,
    u16* __restrict__ xn, float* __restrict__ cosema)
{
    const int wave = threadIdx.x >> 6;
    const int lane = threadIdx.x & 63;
    const int row  = blockIdx.x * 4 + wave; // 0 .. B*T-1

    const float* xr = x + (size_t)row * DDIM + lane * 8;
    float4 v0 = *reinterpret_cast<const float4*>(xr);
    float4 v1 = *reinterpret_cast<const float4*>(xr + 4);
    const float* er = ema + lane * 8;
    float4 e0 = *reinterpret_cast<const float4*>(er);
    float4 e1 = *reinterpret_cast<const float4*>(er + 4);

    float vx[8] = {v0.x,v0.y,v0.z,v0.w,v1.x,v1.y,v1.z,v1.w};
    float ve[8] = {e0.x,e0.y,e0.z,e0.w,e1.x,e1.y,e1.z,e1.w};

    float ssx=0.f, ssg=0.f, dge=0.f, sse=0.f;
    #pragma unroll
    for (int j=0;j<8;++j) {
        float xv = vx[j];
        ssx += xv*xv;
        float gv = gelu_f(xv);
        ssg += gv*gv;
        dge += gv*ve[j];
        sse += ve[j]*ve[j];
    }
    ssx = wave_sum(ssx); ssg = wave_sum(ssg);
    dge = wave_sum(dge); sse = wave_sum(sse);

    float invx = 1.0f / fmaxf(sqrtf(ssx), 1e-12f);
    u16x8 h;
    #pragma unroll
    for (int j=0;j<8;++j) h[j] = f2bf(vx[j] * invx);
    *reinterpret_cast<u16x8*>(xn + (size_t)row * DDIM + lane * 8) = h;

    if (lane == 0) {
        float c = dge / (fmaxf(sqrtf(ssg), 1e-12f) * fmaxf(sqrtf(sse), 1e-12f));
        c = fminf(fmaxf(c, -1.0f), 1.0f);
        cosema[row] = c;
    }
}

// -------- kernel 2: per-batch Xn*Xn^T row-max (diag masked), tiled MFMA --------
__global__ __launch_bounds__(256) void simmax_kernel(
    const u16* __restrict__ xn, float* __restrict__ part)
{
    __shared__ u16 sA[128*64];
    __shared__ u16 sB[128*64];
    __shared__ float pmax2[2][128];

    const int tid  = threadIdx.x;
    const int lane = tid & 63;
    const int w    = tid >> 6;
    const int wm   = w >> 1, wn = w & 1;
    const int ct = blockIdx.x, rt = blockIdx.y, b = blockIdx.z;

    const u16* Ag = xn + ((size_t)b * TDIM + (size_t)rt * 128) * DDIM;
    const u16* Bg = xn + ((size_t)b * TDIM + (size_t)ct * 128) * DDIM;

    const int srow = tid >> 3;        // 0..31
    const int scol = (tid & 7) * 8;   // element col within K-tile

    f32x4 zero = {0.f, 0.f, 0.f, 0.f};
    f32x4 acc[4][4];
    #pragma unroll
    for (int m=0;m<4;++m)
        #pragma unroll
        for (int n=0;n<4;++n) acc[m][n] = zero;

    for (int kt = 0; kt < DDIM; kt += 64) {
        #pragma unroll
        for (int i = 0; i < 4; ++i) {
            load_lds16(Ag + (size_t)(i*32 + srow) * DDIM + kt + scol, &sA[i*2048 + w*512]);
            load_lds16(Bg + (size_t)(i*32 + srow) * DDIM + kt + scol, &sB[i*2048 + w*512]);
        }
        __syncthreads(); // drains vmcnt before LDS consume

        const int roff = lane & 15;
        const int koff = (lane >> 4) * 8;
        #pragma unroll
        for (int kk = 0; kk < 64; kk += 32) {
            bf16x8 af[4], bf[4];
            #pragma unroll
            for (int m=0;m<4;++m)
                af[m] = *reinterpret_cast<const bf16x8*>(&sA[(wm*64 + m*16 + roff)*64 + kk + koff]);
            #pragma unroll
            for (int n=0;n<4;++n)
                bf[n] = *reinterpret_cast<const bf16x8*>(&sB[(wn*64 + n*16 + roff)*64 + kk + koff]);
            #pragma unroll
            for (int m=0;m<4;++m)
                #pragma unroll
                for (int n=0;n<4;++n)
                    acc[m][n] = __builtin_amdgcn_mfma_f32_16x16x32_bf16(af[m], bf[n], acc[m][n], 0, 0, 0);
        }
        __syncthreads();
    }

    // ---- fused epilogue: diagonal mask + row max ----
    // C/D layout (m89/m91): col = lane&15, row = (lane>>4)*4 + reg
    const int gr_base = rt*128 + wm*64;
    const int gc_base = ct*128 + wn*64;
    float rmax[4][4]; // [m][reg]
    #pragma unroll
    for (int m=0;m<4;++m) {
        #pragma unroll
        for (int r=0;r<4;++r) {
            const int grow = gr_base + m*16 + ((lane>>4)<<2) + r;
            float mx = -2.0f;
            #pragma unroll
            for (int n=0;n<4;++n) {
                const int gcol = gc_base + n*16 + (lane & 15);
                float v = acc[m][n][r];
                v = (grow == gcol) ? -2.0f : v;
                mx = fmaxf(mx, v);
            }
            rmax[m][r] = mx;
        }
    }
    // butterfly max across the 16-lane column group
    #pragma unroll
    for (int s = 1; s < 16; s <<= 1) {
        #pragma unroll
        for (int m=0;m<4;++m)
            #pragma unroll
            for (int r=0;r<4;++r)
                rmax[m][r] = fmaxf(rmax[m][r], __shfl_xor(rmax[m][r], s, 64));
    }
    if ((lane & 15) == 0) {
        #pragma unroll
        for (int m=0;m<4;++m)
            #pragma unroll
            for (int r=0;r<4;++r)
                pmax2[wn][wm*64 + m*16 + ((lane>>4)<<2) + r] = rmax[m][r];
    }
    __syncthreads();
    if (tid < 128) {
        float v = fmaxf(pmax2[0][tid], pmax2[1][tid]);
        part[((size_t)b*16 + ct)*TDIM + (size_t)rt*128 + tid] = v;
    }
}

// ---------------- kernel 3: gate + gelu scale ----------------
__global__ __launch_bounds__(256) void finalize_kernel(
    const float* __restrict__ x, const float* __restrict__ part,
    const float* __restrict__ cosema,
    const float* __restrict__ p_log_tau, const float* __restrict__ p_log_sigma,
    const float* __restrict__ p_log_w,
    float* __restrict__ out)
{
    const int wave = threadIdx.x >> 6;
    const int lane = threadIdx.x & 63;
    const int row  = blockIdx.x * 4 + wave;
    const int b = row >> 11;     // /2048
    const int t = row & 2047;

    const float tau   = expf(p_log_tau[0]);
    const float sigma = log1pf(expf(p_log_sigma[0])); // softplus
    const float wgt   = log1pf(expf(p_log_w[0]));

    float nn = -2.0f;
    #pragma unroll
    for (int ctile = 0; ctile < 16; ++ctile)
        nn = fmaxf(nn, part[((size_t)b*16 + ctile)*TDIM + t]);
    nn = fminf(fmaxf(nn, -1.0f), 1.0f);

    const float novelty  = (1.0f - nn) * 0.5f;
    const float surprise = tanhf(sigma * novelty);
    const float gate = expf(-tau * cosema[row]) * (1.0f + wgt * surprise);

    const float* xr = x + (size_t)row * DDIM + lane * 8;
    float* orow = out + (size_t)row * DDIM + lane * 8;
    float4 v0 = *reinterpret_cast<const float4*>(xr);
    float4 v1 = *reinterpret_cast<const float4*>(xr + 4);
    float4 o0, o1;
    o0.x = gelu_f(v0.x) * gate; o0.y = gelu_f(v0.y) * gate;
    o0.z = gelu_f(v0.z) * gate; o0.w = gelu_f(v0.w) * gate;
    o1.x = gelu_f(v1.x) * gate; o1.y = gelu_f(v1.y) * gate;
    o1.z = gelu_f(v1.z) * gate; o1.w = gelu_f(v1.w) * gate;
    *reinterpret_cast<float4*>(orow)     = o0;
    *reinterpret_cast<float4*>(orow + 4) = o1;
}

extern "C" void kernel_launch(void* const* d_in, const int* in_sizes, int n_in,
                              void* d_out, int out_size, void* d_ws, size_t ws_size,
                              hipStream_t stream) {
    const float* x           = (const float*)d_in[0];
    // d_in[1] = logit_decay (unused by reference)
    const float* p_log_tau   = (const float*)d_in[2];
    const float* p_log_sigma = (const float*)d_in[3];
    const float* p_log_w     = (const float*)d_in[4];
    const float* ema         = (const float*)d_in[5];
    float* out = (float*)d_out;

    // Scratch: bf16 x_n lives in the (larger) output buffer until finalize
    // overwrites it; ws holds the partial-max table + cos_ema (~2.2 MB).
    u16*   xn     = (u16*)d_out;                       // B*T*D*2 = 16.8 MB < 33.6 MB
    float* part   = (float*)d_ws;                      // B*16*T*4 = 2 MB
    float* cosema = (float*)((char*)d_ws + (size_t)BATCH*16*TDIM*sizeof(float));

    prep_kernel<<<dim3(BATCH*TDIM/4), 256, 0, stream>>>(x, ema, xn, cosema);
    simmax_kernel<<<dim3(16, 16, BATCH), 256, 0, stream>>>(xn, part);
    finalize_kernel<<<dim3(BATCH*TDIM/4), 256, 0, stream>>>(
        x, part, cosema, p_log_tau, p_log_sigma, p_log_w, out);
}

// Round 2
// 75.724 us; speedup vs baseline: 1.1648x; 1.1648x over previous
//
#include <hip/hip_runtime.h>
#include <math.h>

#define BATCH 8
#define TDIM 2048
#define DDIM 512
#define NT 16            // number of 128-row tiles per batch
#define NTRI (NT*(NT+1)/2)

typedef unsigned short u16;
typedef __bf16 bf16x8 __attribute__((ext_vector_type(8)));
typedef float f32x4 __attribute__((ext_vector_type(4)));
typedef u16 u16x8 __attribute__((ext_vector_type(8)));

// fast tanh via single v_exp_f32: tanh(u) = 1 - 2/(exp(2u)+1)
__device__ __forceinline__ float tanh_fast(float u) {
    float e = __expf(2.0f * u);
    return 1.0f - 2.0f / (e + 1.0f);
}

__device__ __forceinline__ float gelu_f(float x) {
    const float c = 0.7978845608028654f; // sqrt(2/pi)
    return 0.5f * x * (1.0f + tanh_fast(c * (x + 0.044715f * x * x * x)));
}

__device__ __forceinline__ u16 f2bf(float f) {
    unsigned u = __float_as_uint(f);
    return (u16)((u + 0x7FFFu + ((u >> 16) & 1u)) >> 16); // RNE, no NaN inputs
}

__device__ __forceinline__ float wave_sum(float v) {
    #pragma unroll
    for (int s = 1; s < 64; s <<= 1) v += __shfl_xor(v, s, 64);
    return v;
}

__device__ __forceinline__ void load_lds16(const void* g, void* l) {
    __builtin_amdgcn_global_load_lds(
        (const __attribute__((address_space(1))) void*)g,
        (__attribute__((address_space(3))) void*)l, 16, 0, 0);
}

// ---------------- kernel 1: norms, cos_ema, bf16 x_n ----------------
__global__ __launch_bounds__(256) void prep_kernel(
    const float* __restrict__ x, const float* __restrict__ ema,
    u16* __restrict__ xn, float* __restrict__ cosema)
{
    const int wave = threadIdx.x >> 6;
    const int lane = threadIdx.x & 63;
    const int row  = blockIdx.x * 4 + wave; // 0 .. B*T-1

    const float* xr = x + (size_t)row * DDIM + lane * 8;
    float4 v0 = *reinterpret_cast<const float4*>(xr);
    float4 v1 = *reinterpret_cast<const float4*>(xr + 4);
    const float* er = ema + lane * 8;
    float4 e0 = *reinterpret_cast<const float4*>(er);
    float4 e1 = *reinterpret_cast<const float4*>(er + 4);

    float vx[8] = {v0.x,v0.y,v0.z,v0.w,v1.x,v1.y,v1.z,v1.w};
    float ve[8] = {e0.x,e0.y,e0.z,e0.w,e1.x,e1.y,e1.z,e1.w};

    float ssx=0.f, ssg=0.f, dge=0.f, sse=0.f;
    #pragma unroll
    for (int j=0;j<8;++j) {
        float xv = vx[j];
        ssx += xv*xv;
        float gv = gelu_f(xv);
        ssg += gv*gv;
        dge += gv*ve[j];
        sse += ve[j]*ve[j];
    }
    ssx = wave_sum(ssx); ssg = wave_sum(ssg);
    dge = wave_sum(dge); sse = wave_sum(sse);

    float invx = 1.0f / fmaxf(sqrtf(ssx), 1e-12f);
    u16x8 h;
    #pragma unroll
    for (int j=0;j<8;++j) h[j] = f2bf(vx[j] * invx);
    *reinterpret_cast<u16x8*>(xn + (size_t)row * DDIM + lane * 8) = h;

    if (lane == 0) {
        float c = dge / (fmaxf(sqrtf(ssg), 1e-12f) * fmaxf(sqrtf(sse), 1e-12f));
        c = fminf(fmaxf(c, -1.0f), 1.0f);
        cosema[row] = c;
    }
}

// -------- kernel 2: per-batch Xn*Xn^T row-max (diag masked), symmetric tiles --------
// Block handles tile (rt, ct) with rt <= ct. Row-max of the tile fills
// part[b][ct][rt*128 + row]; col-max (== row-max of the transposed tile, by
// symmetry of S) fills part[b][rt][ct*128 + col] (skipped when rt == ct).
__global__ __launch_bounds__(256) void simmax_kernel(
    const u16* __restrict__ xn, float* __restrict__ part)
{
    __shared__ u16 sA[128*64];
    __shared__ u16 sB[128*64];
    __shared__ float prow[2][128];
    __shared__ float pcol[2][128];

    const int tid  = threadIdx.x;
    const int lane = tid & 63;
    const int w    = tid >> 6;
    const int wm   = w >> 1, wn = w & 1;
    const int b = blockIdx.y;

    // decode upper-triangular linear index -> (rt, ct), rt <= ct
    int rem = blockIdx.x, rt = 0;
    while (rem >= (NT - rt)) { rem -= (NT - rt); ++rt; }
    const int ct = rt + rem;

    const u16* Ag = xn + ((size_t)b * TDIM + (size_t)rt * 128) * DDIM;
    const u16* Bg = xn + ((size_t)b * TDIM + (size_t)ct * 128) * DDIM;

    const int srow = tid >> 3;        // 0..31
    const int scol = (tid & 7) * 8;   // element col within K-tile

    f32x4 zero = {0.f, 0.f, 0.f, 0.f};
    f32x4 acc[4][4];
    #pragma unroll
    for (int m=0;m<4;++m)
        #pragma unroll
        for (int n=0;n<4;++n) acc[m][n] = zero;

    for (int kt = 0; kt < DDIM; kt += 64) {
        #pragma unroll
        for (int i = 0; i < 4; ++i) {
            load_lds16(Ag + (size_t)(i*32 + srow) * DDIM + kt + scol, &sA[i*2048 + w*512]);
            load_lds16(Bg + (size_t)(i*32 + srow) * DDIM + kt + scol, &sB[i*2048 + w*512]);
        }
        __syncthreads(); // drains vmcnt before LDS consume

        const int roff = lane & 15;
        const int koff = (lane >> 4) * 8;
        #pragma unroll
        for (int kk = 0; kk < 64; kk += 32) {
            bf16x8 af[4], bf[4];
            #pragma unroll
            for (int m=0;m<4;++m)
                af[m] = *reinterpret_cast<const bf16x8*>(&sA[(wm*64 + m*16 + roff)*64 + kk + koff]);
            #pragma unroll
            for (int n=0;n<4;++n)
                bf[n] = *reinterpret_cast<const bf16x8*>(&sB[(wn*64 + n*16 + roff)*64 + kk + koff]);
            #pragma unroll
            for (int m=0;m<4;++m)
                #pragma unroll
                for (int n=0;n<4;++n)
                    acc[m][n] = __builtin_amdgcn_mfma_f32_16x16x32_bf16(af[m], bf[n], acc[m][n], 0, 0, 0);
        }
        __syncthreads();
    }

    // ---- fused epilogue ----
    // C/D layout (m89/m91): col = lane&15, row = (lane>>4)*4 + reg
    const int gr_base = rt*128 + wm*64;
    const int gc_base = ct*128 + wn*64;
    float rmax[4][4]; // [m][reg]  row-max (diag-masked)
    float cmax[4];    // [n]       col-max (unmasked; only used when rt<ct)
    #pragma unroll
    for (int n=0;n<4;++n) cmax[n] = -2.0f;
    #pragma unroll
    for (int m=0;m<4;++m) {
        #pragma unroll
        for (int r=0;r<4;++r) {
            const int grow = gr_base + m*16 + ((lane>>4)<<2) + r;
            float mx = -2.0f;
            #pragma unroll
            for (int n=0;n<4;++n) {
                const int gcol = gc_base + n*16 + (lane & 15);
                float v = acc[m][n][r];
                cmax[n] = fmaxf(cmax[n], v);
                float vm = (grow == gcol) ? -2.0f : v;
                mx = fmaxf(mx, vm);
            }
            rmax[m][r] = mx;
        }
    }
    // row-max: butterfly across the 16-lane column group (lane>>4 invariant)
    #pragma unroll
    for (int s = 1; s < 16; s <<= 1) {
        #pragma unroll
        for (int m=0;m<4;++m)
            #pragma unroll
            for (int r=0;r<4;++r)
                rmax[m][r] = fmaxf(rmax[m][r], __shfl_xor(rmax[m][r], s, 64));
    }
    if ((lane & 15) == 0) {
        #pragma unroll
        for (int m=0;m<4;++m)
            #pragma unroll
            for (int r=0;r<4;++r)
                prow[wn][wm*64 + m*16 + ((lane>>4)<<2) + r] = rmax[m][r];
    }
    // col-max: butterfly across the 4 row-groups (lane&15 invariant)
    #pragma unroll
    for (int s = 16; s < 64; s <<= 1) {
        #pragma unroll
        for (int n=0;n<4;++n)
            cmax[n] = fmaxf(cmax[n], __shfl_xor(cmax[n], s, 64));
    }
    if (lane < 16) {
        #pragma unroll
        for (int n=0;n<4;++n)
            pcol[wm][wn*64 + n*16 + lane] = cmax[n];
    }
    __syncthreads();
    if (tid < 128) {
        float rv = fmaxf(prow[0][tid], prow[1][tid]);
        part[((size_t)b*NT + ct)*TDIM + (size_t)rt*128 + tid] = rv;
        if (rt != ct) {
            float cv = fmaxf(pcol[0][tid], pcol[1][tid]);
            part[((size_t)b*NT + rt)*TDIM + (size_t)ct*128 + tid] = cv;
        }
    }
}

// ---------------- kernel 3: gate + gelu scale ----------------
__global__ __launch_bounds__(256) void finalize_kernel(
    const float* __restrict__ x, const float* __restrict__ part,
    const float* __restrict__ cosema,
    const float* __restrict__ p_log_tau, const float* __restrict__ p_log_sigma,
    const float* __restrict__ p_log_w,
    float* __restrict__ out)
{
    const int wave = threadIdx.x >> 6;
    const int lane = threadIdx.x & 63;
    const int row  = blockIdx.x * 4 + wave;
    const int b = row >> 11;     // /2048
    const int t = row & 2047;

    const float tau   = __expf(p_log_tau[0]);
    const float sigma = log1pf(__expf(p_log_sigma[0])); // softplus
    const float wgt   = log1pf(__expf(p_log_w[0]));

    float nn = -2.0f;
    #pragma unroll
    for (int ctile = 0; ctile < NT; ++ctile)
        nn = fmaxf(nn, part[((size_t)b*NT + ctile)*TDIM + t]);
    nn = fminf(fmaxf(nn, -1.0f), 1.0f);

    const float novelty  = (1.0f - nn) * 0.5f;
    const float surprise = tanh_fast(sigma * novelty);
    const float gate = __expf(-tau * cosema[row]) * (1.0f + wgt * surprise);

    const float* xr = x + (size_t)row * DDIM + lane * 8;
    float* orow = out + (size_t)row * DDIM + lane * 8;
    float4 v0 = *reinterpret_cast<const float4*>(xr);
    float4 v1 = *reinterpret_cast<const float4*>(xr + 4);
    float4 o0, o1;
    o0.x = gelu_f(v0.x) * gate; o0.y = gelu_f(v0.y) * gate;
    o0.z = gelu_f(v0.z) * gate; o0.w = gelu_f(v0.w) * gate;
    o1.x = gelu_f(v1.x) * gate; o1.y = gelu_f(v1.y) * gate;
    o1.z = gelu_f(v1.z) * gate; o1.w = gelu_f(v1.w) * gate;
    *reinterpret_cast<float4*>(orow)     = o0;
    *reinterpret_cast<float4*>(orow + 4) = o1;
}

extern "C" void kernel_launch(void* const* d_in, const int* in_sizes, int n_in,
                              void* d_out, int out_size, void* d_ws, size_t ws_size,
                              hipStream_t stream) {
    const float* x           = (const float*)d_in[0];
    // d_in[1] = logit_decay (unused by reference)
    const float* p_log_tau   = (const float*)d_in[2];
    const float* p_log_sigma = (const float*)d_in[3];
    const float* p_log_w     = (const float*)d_in[4];
    const float* ema         = (const float*)d_in[5];
    float* out = (float*)d_out;

    // Scratch: bf16 x_n lives in the (larger) output buffer until finalize
    // overwrites it; ws holds the partial-max table + cos_ema (~2.2 MB).
    u16*   xn     = (u16*)d_out;                       // B*T*D*2 = 16.8 MB < 33.6 MB
    float* part   = (float*)d_ws;                      // B*16*T*4 = 2 MB
    float* cosema = (float*)((char*)d_ws + (size_t)BATCH*NT*TDIM*sizeof(float));

    prep_kernel<<<dim3(BATCH*TDIM/4), 256, 0, stream>>>(x, ema, xn, cosema);
    simmax_kernel<<<dim3(NTRI, BATCH), 256, 0, stream>>>(xn, part);
    finalize_kernel<<<dim3(BATCH*TDIM/4), 256, 0, stream>>>(
        x, part, cosema, p_log_tau, p_log_sigma, p_log_w, out);
}

// Round 4
// 70.003 us; speedup vs baseline: 1.2600x; 1.0817x over previous
//
#include <hip/hip_runtime.h>
#include <math.h>

#define BATCH 8
#define TDIM 2048
#define DDIM 512
#define ROWSTR 1024      // u16 elems per packed row slot: [512 xn | 512 gelu]
#define NT 16            // number of 128-row tiles per batch
#define NTRI (NT*(NT+1)/2)

typedef unsigned short u16;
typedef __bf16 bf16x8 __attribute__((ext_vector_type(8)));
typedef float f32x4 __attribute__((ext_vector_type(4)));
typedef u16 u16x8 __attribute__((ext_vector_type(8)));

// fast tanh via single v_exp_f32: tanh(u) = 1 - 2/(exp(2u)+1)
__device__ __forceinline__ float tanh_fast(float u) {
    float e = __expf(2.0f * u);
    return 1.0f - 2.0f / (e + 1.0f);
}

__device__ __forceinline__ float gelu_f(float x) {
    const float c = 0.7978845608028654f; // sqrt(2/pi)
    return 0.5f * x * (1.0f + tanh_fast(c * (x + 0.044715f * x * x * x)));
}

__device__ __forceinline__ u16 f2bf(float f) {
    unsigned u = __float_as_uint(f);
    return (u16)((u + 0x7FFFu + ((u >> 16) & 1u)) >> 16); // RNE, no NaN inputs
}
__device__ __forceinline__ float bf2f(u16 h) {
    return __uint_as_float(((unsigned)h) << 16);
}

__device__ __forceinline__ float wave_sum(float v) {
    #pragma unroll
    for (int s = 1; s < 64; s <<= 1) v += __shfl_xor(v, s, 64);
    return v;
}

__device__ __forceinline__ void load_lds16(const void* g, void* l) {
    __builtin_amdgcn_global_load_lds(
        (const __attribute__((address_space(1))) void*)g,
        (__attribute__((address_space(3))) void*)l, 16, 0, 0);
}

// ---------------- kernel 1: norms, cos_ema, bf16 x_n + bf16 gelu ----------------
__global__ __launch_bounds__(256) void prep_kernel(
    const float* __restrict__ x, const float* __restrict__ ema,
    u16* __restrict__ slots, float* __restrict__ cosema)
{
    const int wave = threadIdx.x >> 6;
    const int lane = threadIdx.x & 63;
    const int row  = blockIdx.x * 4 + wave; // 0 .. B*T-1

    const float* xr = x + (size_t)row * DDIM + lane * 8;
    float4 v0 = *reinterpret_cast<const float4*>(xr);
    float4 v1 = *reinterpret_cast<const float4*>(xr + 4);
    const float* er = ema + lane * 8;
    float4 e0 = *reinterpret_cast<const float4*>(er);
    float4 e1 = *reinterpret_cast<const float4*>(er + 4);

    float vx[8] = {v0.x,v0.y,v0.z,v0.w,v1.x,v1.y,v1.z,v1.w};
    float ve[8] = {e0.x,e0.y,e0.z,e0.w,e1.x,e1.y,e1.z,e1.w};
    float gg[8];

    float ssx=0.f, ssg=0.f, dge=0.f, sse=0.f;
    #pragma unroll
    for (int j=0;j<8;++j) {
        float xv = vx[j];
        ssx += xv*xv;
        float gv = gelu_f(xv);
        gg[j] = gv;
        ssg += gv*gv;
        dge += gv*ve[j];
        sse += ve[j]*ve[j];
    }
    ssx = wave_sum(ssx); ssg = wave_sum(ssg);
    dge = wave_sum(dge); sse = wave_sum(sse);

    float invx = 1.0f / fmaxf(sqrtf(ssx), 1e-12f);
    u16x8 h, hg;
    #pragma unroll
    for (int j=0;j<8;++j) { h[j] = f2bf(vx[j] * invx); hg[j] = f2bf(gg[j]); }
    *reinterpret_cast<u16x8*>(slots + (size_t)row * ROWSTR + lane * 8)       = h;
    *reinterpret_cast<u16x8*>(slots + (size_t)row * ROWSTR + 512 + lane * 8) = hg;

    if (lane == 0) {
        float c = dge / (fmaxf(sqrtf(ssg), 1e-12f) * fmaxf(sqrtf(sse), 1e-12f));
        c = fminf(fmaxf(c, -1.0f), 1.0f);
        cosema[row] = c;
    }
}

// -------- kernel 2: per-batch Xn*Xn^T row-max (diag masked), symmetric tiles --------
// T2-adapted LDS swizzle (rule 21): global_load_lds dest stays LINEAR; the
// per-lane GLOBAL source col-granule is pre-permuted by g ^= (row&7), and the
// ds_read addr applies the same involution, so LDS granule (row,g) holds
// col-granule g^(row&7) and reads retrieve the original data exactly.
__global__ __launch_bounds__(256) void simmax_kernel(
    const u16* __restrict__ xn, float* __restrict__ part)
{
    __shared__ u16 sA[128*64];
    __shared__ u16 sB[128*64];
    __shared__ float prow[2][128];
    __shared__ float pcol[2][128];

    const int tid  = threadIdx.x;
    const int lane = tid & 63;
    const int w    = tid >> 6;
    const int wm   = w >> 1, wn = w & 1;
    const int b = blockIdx.y;

    // decode upper-triangular linear index -> (rt, ct), rt <= ct
    int rem = blockIdx.x, rt = 0;
    while (rem >= (NT - rt)) { rem -= (NT - rt); ++rt; }
    const int ct = rt + rem;

    const u16* Ag = xn + ((size_t)b * TDIM + (size_t)rt * 128) * ROWSTR;
    const u16* Bg = xn + ((size_t)b * TDIM + (size_t)ct * 128) * ROWSTR;

    const int srow = tid >> 3;                               // 0..31 within chunk pair
    const int scol = (((tid & 7) ^ ((tid >> 3) & 7))) * 8;   // pre-swizzled src granule

    f32x4 zero = {0.f, 0.f, 0.f, 0.f};
    f32x4 acc[4][4];
    #pragma unroll
    for (int m=0;m<4;++m)
        #pragma unroll
        for (int n=0;n<4;++n) acc[m][n] = zero;

    const int roff  = lane & 15;
    const int sw    = roff & 7;      // read-side XOR (row&7 == roff&7)
    const int klane = lane >> 4;

    for (int kt = 0; kt < DDIM; kt += 64) {
        #pragma unroll
        for (int i = 0; i < 4; ++i) {
            load_lds16(Ag + (size_t)(i*32 + srow) * ROWSTR + kt + scol, &sA[i*2048 + w*512]);
            load_lds16(Bg + (size_t)(i*32 + srow) * ROWSTR + kt + scol, &sB[i*2048 + w*512]);
        }
        __syncthreads(); // drains vmcnt before LDS consume

        #pragma unroll
        for (int kk = 0; kk < 64; kk += 32) {
            const int koffs = ((((kk >> 3) + klane) ^ sw)) * 8; // swizzled granule
            bf16x8 af[4], bf[4];
            #pragma unroll
            for (int m=0;m<4;++m)
                af[m] = *reinterpret_cast<const bf16x8*>(&sA[(wm*64 + m*16 + roff)*64 + koffs]);
            #pragma unroll
            for (int n=0;n<4;++n)
                bf[n] = *reinterpret_cast<const bf16x8*>(&sB[(wn*64 + n*16 + roff)*64 + koffs]);
            #pragma unroll
            for (int m=0;m<4;++m)
                #pragma unroll
                for (int n=0;n<4;++n)
                    acc[m][n] = __builtin_amdgcn_mfma_f32_16x16x32_bf16(af[m], bf[n], acc[m][n], 0, 0, 0);
        }
        __syncthreads();
    }

    // ---- fused epilogue ----
    // C/D layout (m89/m91): col = lane&15, row = (lane>>4)*4 + reg
    const int gr_base = rt*128 + wm*64;
    const int gc_base = ct*128 + wn*64;
    float rmax[4][4]; // [m][reg]  row-max (diag-masked)
    float cmax[4];    // [n]       col-max (unmasked; used when rt<ct)
    #pragma unroll
    for (int n=0;n<4;++n) cmax[n] = -2.0f;
    #pragma unroll
    for (int m=0;m<4;++m) {
        #pragma unroll
        for (int r=0;r<4;++r) {
            const int grow = gr_base + m*16 + ((lane>>4)<<2) + r;
            float mx = -2.0f;
            #pragma unroll
            for (int n=0;n<4;++n) {
                const int gcol = gc_base + n*16 + (lane & 15);
                float v = acc[m][n][r];
                cmax[n] = fmaxf(cmax[n], v);
                float vm = (grow == gcol) ? -2.0f : v;
                mx = fmaxf(mx, vm);
            }
            rmax[m][r] = mx;
        }
    }
    // row-max: butterfly across the 16-lane column group
    #pragma unroll
    for (int s = 1; s < 16; s <<= 1) {
        #pragma unroll
        for (int m=0;m<4;++m)
            #pragma unroll
            for (int r=0;r<4;++r)
                rmax[m][r] = fmaxf(rmax[m][r], __shfl_xor(rmax[m][r], s, 64));
    }
    if ((lane & 15) == 0) {
        #pragma unroll
        for (int m=0;m<4;++m)
            #pragma unroll
            for (int r=0;r<4;++r)
                prow[wn][wm*64 + m*16 + ((lane>>4)<<2) + r] = rmax[m][r];
    }
    // col-max: butterfly across the 4 row-groups
    #pragma unroll
    for (int s = 16; s < 64; s <<= 1) {
        #pragma unroll
        for (int n=0;n<4;++n)
            cmax[n] = fmaxf(cmax[n], __shfl_xor(cmax[n], s, 64));
    }
    if (lane < 16) {
        #pragma unroll
        for (int n=0;n<4;++n)
            pcol[wm][wn*64 + n*16 + lane] = cmax[n];
    }
    __syncthreads();
    if (tid < 128) {
        float rv = fmaxf(prow[0][tid], prow[1][tid]);
        part[((size_t)b*NT + ct)*TDIM + (size_t)rt*128 + tid] = rv;
        if (rt != ct) {
            float cv = fmaxf(pcol[0][tid], pcol[1][tid]);
            part[((size_t)b*NT + rt)*TDIM + (size_t)ct*128 + tid] = cv;
        }
    }
}

// ---------------- kernel 3: gate * cached gelu ----------------
// slots aliases d_out: row r's slot = bytes [r*2048, r*2048+2048):
// first 1024 B = xn (dead now), next 1024 B = gelu bf16. Each wave reads its
// own row's gelu then overwrites its own slot with fp32 out — the store data
// depends on the load, and a wave's load instruction issues for all 64 lanes
// before its store, so the in-slot overwrite is race-free.
__global__ __launch_bounds__(256) void finalize_kernel(
    u16* slots,
    const float* __restrict__ part, const float* __restrict__ cosema,
    const float* __restrict__ p_log_tau, const float* __restrict__ p_log_sigma,
    const float* __restrict__ p_log_w)
{
    const int wave = threadIdx.x >> 6;
    const int lane = threadIdx.x & 63;
    const int row  = blockIdx.x * 4 + wave;
    const int b = row >> 11;     // /2048
    const int t = row & 2047;

    const float tau   = __expf(p_log_tau[0]);
    const float sigma = log1pf(__expf(p_log_sigma[0])); // softplus
    const float wgt   = log1pf(__expf(p_log_w[0]));

    float nn = -2.0f;
    #pragma unroll
    for (int ctile = 0; ctile < NT; ++ctile)
        nn = fmaxf(nn, part[((size_t)b*NT + ctile)*TDIM + t]);
    nn = fminf(fmaxf(nn, -1.0f), 1.0f);

    const float novelty  = (1.0f - nn) * 0.5f;
    const float surprise = tanh_fast(sigma * novelty);
    const float gate = __expf(-tau * cosema[row]) * (1.0f + wgt * surprise);

    u16x8 hg = *reinterpret_cast<const u16x8*>(slots + (size_t)row * ROWSTR + 512 + lane * 8);
    float4 o0, o1;
    o0.x = bf2f(hg[0]) * gate; o0.y = bf2f(hg[1]) * gate;
    o0.z = bf2f(hg[2]) * gate; o0.w = bf2f(hg[3]) * gate;
    o1.x = bf2f(hg[4]) * gate; o1.y = bf2f(hg[5]) * gate;
    o1.z = bf2f(hg[6]) * gate; o1.w = bf2f(hg[7]) * gate;
    float* orow = reinterpret_cast<float*>(slots) + (size_t)row * DDIM + lane * 8;
    *reinterpret_cast<float4*>(orow)     = o0;
    *reinterpret_cast<float4*>(orow + 4) = o1;
}

extern "C" void kernel_launch(void* const* d_in, const int* in_sizes, int n_in,
                              void* d_out, int out_size, void* d_ws, size_t ws_size,
                              hipStream_t stream) {
    const float* x           = (const float*)d_in[0];
    // d_in[1] = logit_decay (unused by reference)
    const float* p_log_tau   = (const float*)d_in[2];
    const float* p_log_sigma = (const float*)d_in[3];
    const float* p_log_w     = (const float*)d_in[4];
    const float* ema         = (const float*)d_in[5];

    // d_out doubles as scratch: per-row 2048-B slots hold [xn bf16 | gelu bf16]
    // until finalize overwrites each slot with the fp32 output row.
    u16*   slots  = (u16*)d_out;                       // B*T*ROWSTR u16 = 33.6 MB
    float* part   = (float*)d_ws;                      // B*NT*T*4 = 2 MB
    float* cosema = (float*)((char*)d_ws + (size_t)BATCH*NT*TDIM*sizeof(float));

    prep_kernel<<<dim3(BATCH*TDIM/4), 256, 0, stream>>>(x, ema, slots, cosema);
    simmax_kernel<<<dim3(NTRI, BATCH), 256, 0, stream>>>(slots, part);
    finalize_kernel<<<dim3(BATCH*TDIM/4), 256, 0, stream>>>(
        slots, part, cosema, p_log_tau, p_log_sigma, p_log_w);
}

// Round 5
// 67.134 us; speedup vs baseline: 1.3138x; 1.0427x over previous
//
#include <hip/hip_runtime.h>
#include <math.h>

#define BATCH 8
#define TDIM 2048
#define DDIM 512
#define ROWSTR 1024      // u16 elems per packed row slot: [512 xn | 512 gelu]
#define NT 16            // number of 128-row tiles per batch
#define NTRI (NT*(NT+1)/2)

typedef unsigned short u16;
typedef __bf16 bf16x8 __attribute__((ext_vector_type(8)));
typedef float f32x4 __attribute__((ext_vector_type(4)));
typedef u16 u16x8 __attribute__((ext_vector_type(8)));

// fast tanh via single v_exp_f32: tanh(u) = 1 - 2/(exp(2u)+1)
__device__ __forceinline__ float tanh_fast(float u) {
    float e = __expf(2.0f * u);
    return 1.0f - 2.0f / (e + 1.0f);
}

__device__ __forceinline__ float gelu_f(float x) {
    const float c = 0.7978845608028654f; // sqrt(2/pi)
    return 0.5f * x * (1.0f + tanh_fast(c * (x + 0.044715f * x * x * x)));
}

__device__ __forceinline__ u16 f2bf(float f) {
    unsigned u = __float_as_uint(f);
    return (u16)((u + 0x7FFFu + ((u >> 16) & 1u)) >> 16); // RNE, no NaN inputs
}
__device__ __forceinline__ float bf2f(u16 h) {
    return __uint_as_float(((unsigned)h) << 16);
}

__device__ __forceinline__ float wave_sum(float v) {
    #pragma unroll
    for (int s = 1; s < 64; s <<= 1) v += __shfl_xor(v, s, 64);
    return v;
}

__device__ __forceinline__ void load_lds16(const void* g, void* l) {
    __builtin_amdgcn_global_load_lds(
        (const __attribute__((address_space(1))) void*)g,
        (__attribute__((address_space(3))) void*)l, 16, 0, 0);
}

// ---------------- kernel 1: norms, cos_ema, bf16 x_n + bf16 gelu ----------------
__global__ __launch_bounds__(256) void prep_kernel(
    const float* __restrict__ x, const float* __restrict__ ema,
    u16* __restrict__ slots, float* __restrict__ cosema)
{
    const int wave = threadIdx.x >> 6;
    const int lane = threadIdx.x & 63;
    const int row  = blockIdx.x * 4 + wave; // 0 .. B*T-1

    const float* xr = x + (size_t)row * DDIM + lane * 8;
    float4 v0 = *reinterpret_cast<const float4*>(xr);
    float4 v1 = *reinterpret_cast<const float4*>(xr + 4);
    const float* er = ema + lane * 8;
    float4 e0 = *reinterpret_cast<const float4*>(er);
    float4 e1 = *reinterpret_cast<const float4*>(er + 4);

    float vx[8] = {v0.x,v0.y,v0.z,v0.w,v1.x,v1.y,v1.z,v1.w};
    float ve[8] = {e0.x,e0.y,e0.z,e0.w,e1.x,e1.y,e1.z,e1.w};
    float gg[8];

    float ssx=0.f, ssg=0.f, dge=0.f, sse=0.f;
    #pragma unroll
    for (int j=0;j<8;++j) {
        float xv = vx[j];
        ssx += xv*xv;
        float gv = gelu_f(xv);
        gg[j] = gv;
        ssg += gv*gv;
        dge += gv*ve[j];
        sse += ve[j]*ve[j];
    }
    ssx = wave_sum(ssx); ssg = wave_sum(ssg);
    dge = wave_sum(dge); sse = wave_sum(sse);

    float invx = 1.0f / fmaxf(sqrtf(ssx), 1e-12f);
    u16x8 h, hg;
    #pragma unroll
    for (int j=0;j<8;++j) { h[j] = f2bf(vx[j] * invx); hg[j] = f2bf(gg[j]); }
    *reinterpret_cast<u16x8*>(slots + (size_t)row * ROWSTR + lane * 8)       = h;
    *reinterpret_cast<u16x8*>(slots + (size_t)row * ROWSTR + 512 + lane * 8) = hg;

    if (lane == 0) {
        float c = dge / (fmaxf(sqrtf(ssg), 1e-12f) * fmaxf(sqrtf(sse), 1e-12f));
        c = fminf(fmaxf(c, -1.0f), 1.0f);
        cosema[row] = c;
    }
}

// -------- kernel 2: per-batch Xn*Xn^T row-max (diag masked), symmetric tiles --------
// T1 batch-per-XCD mapping: dispatch round-robins consecutive blockIdx across
// the 8 XCDs (m157/m192), so batch = blockIdx.x % 8 pins each batch's 2 MB xn
// working set to one XCD's 4 MiB L2 (16 MB total was thrashing all 8 L2s:
// 70 MB FETCH vs 16 MB ideal). Correctness-independent of the actual mapping.
// T2-adapted LDS swizzle (rule 21): global_load_lds dest stays LINEAR; the
// per-lane GLOBAL source col-granule is pre-permuted by g ^= (row&7), and the
// ds_read addr applies the same involution.
__global__ __launch_bounds__(256) void simmax_kernel(
    const u16* __restrict__ xn, float* __restrict__ part)
{
    __shared__ u16 sA[128*64];
    __shared__ u16 sB[128*64];
    __shared__ float prow[2][128];
    __shared__ float pcol[2][128];

    const int tid  = threadIdx.x;
    const int lane = tid & 63;
    const int w    = tid >> 6;
    const int wm   = w >> 1, wn = w & 1;

    const int b = blockIdx.x & 7;        // batch == XCD (round-robin dispatch)
    // decode upper-triangular linear index -> (rt, ct), rt <= ct
    int rem = blockIdx.x >> 3, rt = 0;
    while (rem >= (NT - rt)) { rem -= (NT - rt); ++rt; }
    const int ct = rt + rem;

    const u16* Ag = xn + ((size_t)b * TDIM + (size_t)rt * 128) * ROWSTR;
    const u16* Bg = xn + ((size_t)b * TDIM + (size_t)ct * 128) * ROWSTR;

    const int srow = tid >> 3;                               // 0..31 within chunk pair
    const int scol = (((tid & 7) ^ ((tid >> 3) & 7))) * 8;   // pre-swizzled src granule

    f32x4 zero = {0.f, 0.f, 0.f, 0.f};
    f32x4 acc[4][4];
    #pragma unroll
    for (int m=0;m<4;++m)
        #pragma unroll
        for (int n=0;n<4;++n) acc[m][n] = zero;

    const int roff  = lane & 15;
    const int sw    = roff & 7;      // read-side XOR (row&7 == roff&7)
    const int klane = lane >> 4;

    for (int kt = 0; kt < DDIM; kt += 64) {
        #pragma unroll
        for (int i = 0; i < 4; ++i) {
            load_lds16(Ag + (size_t)(i*32 + srow) * ROWSTR + kt + scol, &sA[i*2048 + w*512]);
            load_lds16(Bg + (size_t)(i*32 + srow) * ROWSTR + kt + scol, &sB[i*2048 + w*512]);
        }
        __syncthreads(); // drains vmcnt before LDS consume

        #pragma unroll
        for (int kk = 0; kk < 64; kk += 32) {
            const int koffs = ((((kk >> 3) + klane) ^ sw)) * 8; // swizzled granule
            bf16x8 af[4], bf[4];
            #pragma unroll
            for (int m=0;m<4;++m)
                af[m] = *reinterpret_cast<const bf16x8*>(&sA[(wm*64 + m*16 + roff)*64 + koffs]);
            #pragma unroll
            for (int n=0;n<4;++n)
                bf[n] = *reinterpret_cast<const bf16x8*>(&sB[(wn*64 + n*16 + roff)*64 + koffs]);
            #pragma unroll
            for (int m=0;m<4;++m)
                #pragma unroll
                for (int n=0;n<4;++n)
                    acc[m][n] = __builtin_amdgcn_mfma_f32_16x16x32_bf16(af[m], bf[n], acc[m][n], 0, 0, 0);
        }
        __syncthreads();
    }

    // ---- fused epilogue ----
    // C/D layout (m89/m91): col = lane&15, row = (lane>>4)*4 + reg
    const int gr_base = rt*128 + wm*64;
    const int gc_base = ct*128 + wn*64;
    float rmax[4][4]; // [m][reg]  row-max (diag-masked)
    float cmax[4];    // [n]       col-max (unmasked; used when rt<ct)
    #pragma unroll
    for (int n=0;n<4;++n) cmax[n] = -2.0f;
    #pragma unroll
    for (int m=0;m<4;++m) {
        #pragma unroll
        for (int r=0;r<4;++r) {
            const int grow = gr_base + m*16 + ((lane>>4)<<2) + r;
            float mx = -2.0f;
            #pragma unroll
            for (int n=0;n<4;++n) {
                const int gcol = gc_base + n*16 + (lane & 15);
                float v = acc[m][n][r];
                cmax[n] = fmaxf(cmax[n], v);
                float vm = (grow == gcol) ? -2.0f : v;
                mx = fmaxf(mx, vm);
            }
            rmax[m][r] = mx;
        }
    }
    // row-max: butterfly across the 16-lane column group
    #pragma unroll
    for (int s = 1; s < 16; s <<= 1) {
        #pragma unroll
        for (int m=0;m<4;++m)
            #pragma unroll
            for (int r=0;r<4;++r)
                rmax[m][r] = fmaxf(rmax[m][r], __shfl_xor(rmax[m][r], s, 64));
    }
    if ((lane & 15) == 0) {
        #pragma unroll
        for (int m=0;m<4;++m)
            #pragma unroll
            for (int r=0;r<4;++r)
                prow[wn][wm*64 + m*16 + ((lane>>4)<<2) + r] = rmax[m][r];
    }
    // col-max: butterfly across the 4 row-groups
    #pragma unroll
    for (int s = 16; s < 64; s <<= 1) {
        #pragma unroll
        for (int n=0;n<4;++n)
            cmax[n] = fmaxf(cmax[n], __shfl_xor(cmax[n], s, 64));
    }
    if (lane < 16) {
        #pragma unroll
        for (int n=0;n<4;++n)
            pcol[wm][wn*64 + n*16 + lane] = cmax[n];
    }
    __syncthreads();
    if (tid < 128) {
        float rv = fmaxf(prow[0][tid], prow[1][tid]);
        part[((size_t)b*NT + ct)*TDIM + (size_t)rt*128 + tid] = rv;
        if (rt != ct) {
            float cv = fmaxf(pcol[0][tid], pcol[1][tid]);
            part[((size_t)b*NT + rt)*TDIM + (size_t)ct*128 + tid] = cv;
        }
    }
}

// ---------------- kernel 3: gate * cached gelu ----------------
// slots aliases d_out: row r's slot = bytes [r*2048, r*2048+2048):
// first 1024 B = xn (dead now), next 1024 B = gelu bf16. Each wave reads its
// own row's gelu then overwrites its own slot with fp32 out — the store data
// depends on the load, so the in-slot overwrite is race-free.
__global__ __launch_bounds__(256) void finalize_kernel(
    u16* slots,
    const float* __restrict__ part, const float* __restrict__ cosema,
    const float* __restrict__ p_log_tau, const float* __restrict__ p_log_sigma,
    const float* __restrict__ p_log_w)
{
    const int wave = threadIdx.x >> 6;
    const int lane = threadIdx.x & 63;
    const int row  = blockIdx.x * 4 + wave;
    const int b = row >> 11;     // /2048
    const int t = row & 2047;

    const float tau   = __expf(p_log_tau[0]);
    const float sigma = log1pf(__expf(p_log_sigma[0])); // softplus
    const float wgt   = log1pf(__expf(p_log_w[0]));

    float nn = -2.0f;
    #pragma unroll
    for (int ctile = 0; ctile < NT; ++ctile)
        nn = fmaxf(nn, part[((size_t)b*NT + ctile)*TDIM + t]);
    nn = fminf(fmaxf(nn, -1.0f), 1.0f);

    const float novelty  = (1.0f - nn) * 0.5f;
    const float surprise = tanh_fast(sigma * novelty);
    const float gate = __expf(-tau * cosema[row]) * (1.0f + wgt * surprise);

    u16x8 hg = *reinterpret_cast<const u16x8*>(slots + (size_t)row * ROWSTR + 512 + lane * 8);
    float4 o0, o1;
    o0.x = bf2f(hg[0]) * gate; o0.y = bf2f(hg[1]) * gate;
    o0.z = bf2f(hg[2]) * gate; o0.w = bf2f(hg[3]) * gate;
    o1.x = bf2f(hg[4]) * gate; o1.y = bf2f(hg[5]) * gate;
    o1.z = bf2f(hg[6]) * gate; o1.w = bf2f(hg[7]) * gate;
    float* orow = reinterpret_cast<float*>(slots) + (size_t)row * DDIM + lane * 8;
    *reinterpret_cast<float4*>(orow)     = o0;
    *reinterpret_cast<float4*>(orow + 4) = o1;
}

extern "C" void kernel_launch(void* const* d_in, const int* in_sizes, int n_in,
                              void* d_out, int out_size, void* d_ws, size_t ws_size,
                              hipStream_t stream) {
    const float* x           = (const float*)d_in[0];
    // d_in[1] = logit_decay (unused by reference)
    const float* p_log_tau   = (const float*)d_in[2];
    const float* p_log_sigma = (const float*)d_in[3];
    const float* p_log_w     = (const float*)d_in[4];
    const float* ema         = (const float*)d_in[5];

    // d_out doubles as scratch: per-row 2048-B slots hold [xn bf16 | gelu bf16]
    // until finalize overwrites each slot with the fp32 output row.
    u16*   slots  = (u16*)d_out;                       // B*T*ROWSTR u16 = 33.6 MB
    float* part   = (float*)d_ws;                      // B*NT*T*4 = 2 MB
    float* cosema = (float*)((char*)d_ws + (size_t)BATCH*NT*TDIM*sizeof(float));

    prep_kernel<<<dim3(BATCH*TDIM/4), 256, 0, stream>>>(x, ema, slots, cosema);
    simmax_kernel<<<dim3(NTRI*BATCH), 256, 0, stream>>>(slots, part);
    finalize_kernel<<<dim3(BATCH*TDIM/4), 256, 0, stream>>>(
        slots, part, cosema, p_log_tau, p_log_sigma, p_log_w);
}

// Round 6
// 61.683 us; speedup vs baseline: 1.4299x; 1.0884x over previous
//
#include <hip/hip_runtime.h>
#include <math.h>

#define BATCH 8
#define TDIM 2048
#define DDIM 512
#define ROWSTR 1024      // u16 elems per packed row slot: [512 xn | 512 gelu]
#define NT 16            // number of 128-row tiles per batch
#define NTRI (NT*(NT+1)/2)

typedef unsigned short u16;
typedef __bf16 bf16x8 __attribute__((ext_vector_type(8)));
typedef float f32x4 __attribute__((ext_vector_type(4)));
typedef u16 u16x8 __attribute__((ext_vector_type(8)));

// fast tanh via single v_exp_f32: tanh(u) = 1 - 2/(exp(2u)+1)
__device__ __forceinline__ float tanh_fast(float u) {
    float e = __expf(2.0f * u);
    return 1.0f - 2.0f / (e + 1.0f);
}

__device__ __forceinline__ float gelu_f(float x) {
    const float c = 0.7978845608028654f; // sqrt(2/pi)
    return 0.5f * x * (1.0f + tanh_fast(c * (x + 0.044715f * x * x * x)));
}

__device__ __forceinline__ u16 f2bf(float f) {
    unsigned u = __float_as_uint(f);
    return (u16)((u + 0x7FFFu + ((u >> 16) & 1u)) >> 16); // RNE, no NaN inputs
}
__device__ __forceinline__ float bf2f(u16 h) {
    return __uint_as_float(((unsigned)h) << 16);
}

__device__ __forceinline__ float wave_sum(float v) {
    #pragma unroll
    for (int s = 1; s < 64; s <<= 1) v += __shfl_xor(v, s, 64);
    return v;
}

__device__ __forceinline__ void load_lds16(const void* g, void* l) {
    __builtin_amdgcn_global_load_lds(
        (const __attribute__((address_space(1))) void*)g,
        (__attribute__((address_space(3))) void*)l, 16, 0, 0);
}

// ---------------- kernel 1: norms, cos_ema, bf16 x_n + bf16 gelu ----------------
__global__ __launch_bounds__(256) void prep_kernel(
    const float* __restrict__ x, const float* __restrict__ ema,
    u16* __restrict__ slots, float* __restrict__ cosema)
{
    const int wave = threadIdx.x >> 6;
    const int lane = threadIdx.x & 63;
    const int row  = blockIdx.x * 4 + wave; // 0 .. B*T-1

    const float* xr = x + (size_t)row * DDIM + lane * 8;
    float4 v0 = *reinterpret_cast<const float4*>(xr);
    float4 v1 = *reinterpret_cast<const float4*>(xr + 4);
    const float* er = ema + lane * 8;
    float4 e0 = *reinterpret_cast<const float4*>(er);
    float4 e1 = *reinterpret_cast<const float4*>(er + 4);

    float vx[8] = {v0.x,v0.y,v0.z,v0.w,v1.x,v1.y,v1.z,v1.w};
    float ve[8] = {e0.x,e0.y,e0.z,e0.w,e1.x,e1.y,e1.z,e1.w};
    float gg[8];

    float ssx=0.f, ssg=0.f, dge=0.f, sse=0.f;
    #pragma unroll
    for (int j=0;j<8;++j) {
        float xv = vx[j];
        ssx += xv*xv;
        float gv = gelu_f(xv);
        gg[j] = gv;
        ssg += gv*gv;
        dge += gv*ve[j];
        sse += ve[j]*ve[j];
    }
    ssx = wave_sum(ssx); ssg = wave_sum(ssg);
    dge = wave_sum(dge); sse = wave_sum(sse);

    float invx = 1.0f / fmaxf(sqrtf(ssx), 1e-12f);
    u16x8 h, hg;
    #pragma unroll
    for (int j=0;j<8;++j) { h[j] = f2bf(vx[j] * invx); hg[j] = f2bf(gg[j]); }
    *reinterpret_cast<u16x8*>(slots + (size_t)row * ROWSTR + lane * 8)       = h;
    *reinterpret_cast<u16x8*>(slots + (size_t)row * ROWSTR + 512 + lane * 8) = hg;

    if (lane == 0) {
        float c = dge / (fmaxf(sqrtf(ssg), 1e-12f) * fmaxf(sqrtf(sse), 1e-12f));
        c = fminf(fmaxf(c, -1.0f), 1.0f);
        cosema[row] = c;
    }
}

// -------- kernel 2: per-batch Xn*Xn^T row-max (diag masked), symmetric tiles --------
// T1 batch-per-XCD mapping (b = blockIdx.x % 8) pins each batch's 2 MB working
// set to one XCD's L2. T2-adapted source-swizzle kept (free, conflict-free
// ds_read). NEW (T3-minimum): double-buffered LDS — STAGE(next) is issued
// BEFORE the ds_read+MFMA of the current buffer, so the staging latency hides
// under compute; the single __syncthreads() per K-step then drains mostly-
// completed loads. Hazards: reads of buf^1 finished before the previous
// barrier (overwrite safe); stage of buf[cur] drained by the previous
// barrier's vmcnt(0) (read safe).
__global__ __launch_bounds__(256) void simmax_kernel(
    const u16* __restrict__ xn, float* __restrict__ part)
{
    __shared__ u16 sA[2][128*64];
    __shared__ u16 sB[2][128*64];
    __shared__ float prow[2][128];
    __shared__ float pcol[2][128];

    const int tid  = threadIdx.x;
    const int lane = tid & 63;
    const int w    = tid >> 6;
    const int wm   = w >> 1, wn = w & 1;

    const int b = blockIdx.x & 7;        // batch == XCD (round-robin dispatch)
    // decode upper-triangular linear index -> (rt, ct), rt <= ct
    int rem = blockIdx.x >> 3, rt = 0;
    while (rem >= (NT - rt)) { rem -= (NT - rt); ++rt; }
    const int ct = rt + rem;

    const u16* Ag = xn + ((size_t)b * TDIM + (size_t)rt * 128) * ROWSTR;
    const u16* Bg = xn + ((size_t)b * TDIM + (size_t)ct * 128) * ROWSTR;

    const int srow = tid >> 3;                               // 0..31 within chunk pair
    const int scol = (((tid & 7) ^ ((tid >> 3) & 7))) * 8;   // pre-swizzled src granule

    f32x4 zero = {0.f, 0.f, 0.f, 0.f};
    f32x4 acc[4][4];
    #pragma unroll
    for (int m=0;m<4;++m)
        #pragma unroll
        for (int n=0;n<4;++n) acc[m][n] = zero;

    const int roff  = lane & 15;
    const int sw    = roff & 7;      // read-side XOR (row&7 == roff&7)
    const int klane = lane >> 4;

    auto stage = [&](int buf, int kt) {
        #pragma unroll
        for (int i = 0; i < 4; ++i) {
            load_lds16(Ag + (size_t)(i*32 + srow) * ROWSTR + kt + scol, &sA[buf][i*2048 + w*512]);
            load_lds16(Bg + (size_t)(i*32 + srow) * ROWSTR + kt + scol, &sB[buf][i*2048 + w*512]);
        }
    };

    stage(0, 0);
    __syncthreads();                     // vmcnt(0) drain: buf0 ready

    for (int kt64 = 0; kt64 < 8; ++kt64) {
        const int cur = kt64 & 1;
        if (kt64 < 7) stage(cur ^ 1, (kt64 + 1) * 64);   // issue-early: hides under MFMA

        #pragma unroll
        for (int kk = 0; kk < 64; kk += 32) {
            const int koffs = ((((kk >> 3) + klane) ^ sw)) * 8; // swizzled granule
            bf16x8 af[4], bf[4];
            #pragma unroll
            for (int m=0;m<4;++m)
                af[m] = *reinterpret_cast<const bf16x8*>(&sA[cur][(wm*64 + m*16 + roff)*64 + koffs]);
            #pragma unroll
            for (int n=0;n<4;++n)
                bf[n] = *reinterpret_cast<const bf16x8*>(&sB[cur][(wn*64 + n*16 + roff)*64 + koffs]);
            #pragma unroll
            for (int m=0;m<4;++m)
                #pragma unroll
                for (int n=0;n<4;++n)
                    acc[m][n] = __builtin_amdgcn_mfma_f32_16x16x32_bf16(af[m], bf[n], acc[m][n], 0, 0, 0);
        }
        __syncthreads();                 // next-tile loads drained + read/overwrite fence
    }

    // ---- fused epilogue ----
    // C/D layout (m89/m91): col = lane&15, row = (lane>>4)*4 + reg
    const int gr_base = rt*128 + wm*64;
    const int gc_base = ct*128 + wn*64;
    float rmax[4][4]; // [m][reg]  row-max (diag-masked)
    float cmax[4];    // [n]       col-max (unmasked; used when rt<ct)
    #pragma unroll
    for (int n=0;n<4;++n) cmax[n] = -2.0f;
    #pragma unroll
    for (int m=0;m<4;++m) {
        #pragma unroll
        for (int r=0;r<4;++r) {
            const int grow = gr_base + m*16 + ((lane>>4)<<2) + r;
            float mx = -2.0f;
            #pragma unroll
            for (int n=0;n<4;++n) {
                const int gcol = gc_base + n*16 + (lane & 15);
                float v = acc[m][n][r];
                cmax[n] = fmaxf(cmax[n], v);
                float vm = (grow == gcol) ? -2.0f : v;
                mx = fmaxf(mx, vm);
            }
            rmax[m][r] = mx;
        }
    }
    // row-max: butterfly across the 16-lane column group
    #pragma unroll
    for (int s = 1; s < 16; s <<= 1) {
        #pragma unroll
        for (int m=0;m<4;++m)
            #pragma unroll
            for (int r=0;r<4;++r)
                rmax[m][r] = fmaxf(rmax[m][r], __shfl_xor(rmax[m][r], s, 64));
    }
    if ((lane & 15) == 0) {
        #pragma unroll
        for (int m=0;m<4;++m)
            #pragma unroll
            for (int r=0;r<4;++r)
                prow[wn][wm*64 + m*16 + ((lane>>4)<<2) + r] = rmax[m][r];
    }
    // col-max: butterfly across the 4 row-groups
    #pragma unroll
    for (int s = 16; s < 64; s <<= 1) {
        #pragma unroll
        for (int n=0;n<4;++n)
            cmax[n] = fmaxf(cmax[n], __shfl_xor(cmax[n], s, 64));
    }
    if (lane < 16) {
        #pragma unroll
        for (int n=0;n<4;++n)
            pcol[wm][wn*64 + n*16 + lane] = cmax[n];
    }
    __syncthreads();
    if (tid < 128) {
        float rv = fmaxf(prow[0][tid], prow[1][tid]);
        part[((size_t)b*NT + ct)*TDIM + (size_t)rt*128 + tid] = rv;
        if (rt != ct) {
            float cv = fmaxf(pcol[0][tid], pcol[1][tid]);
            part[((size_t)b*NT + rt)*TDIM + (size_t)ct*128 + tid] = cv;
        }
    }
}

// ---------------- kernel 3: gate * cached gelu ----------------
// slots aliases d_out: row r's slot = bytes [r*2048, r*2048+2048):
// first 1024 B = xn (dead now), next 1024 B = gelu bf16. Each wave reads its
// own row's gelu then overwrites its own slot with fp32 out — the store data
// depends on the load, so the in-slot overwrite is race-free.
__global__ __launch_bounds__(256) void finalize_kernel(
    u16* slots,
    const float* __restrict__ part, const float* __restrict__ cosema,
    const float* __restrict__ p_log_tau, const float* __restrict__ p_log_sigma,
    const float* __restrict__ p_log_w)
{
    const int wave = threadIdx.x >> 6;
    const int lane = threadIdx.x & 63;
    const int row  = blockIdx.x * 4 + wave;
    const int b = row >> 11;     // /2048
    const int t = row & 2047;

    const float tau   = __expf(p_log_tau[0]);
    const float sigma = log1pf(__expf(p_log_sigma[0])); // softplus
    const float wgt   = log1pf(__expf(p_log_w[0]));

    float nn = -2.0f;
    #pragma unroll
    for (int ctile = 0; ctile < NT; ++ctile)
        nn = fmaxf(nn, part[((size_t)b*NT + ctile)*TDIM + t]);
    nn = fminf(fmaxf(nn, -1.0f), 1.0f);

    const float novelty  = (1.0f - nn) * 0.5f;
    const float surprise = tanh_fast(sigma * novelty);
    const float gate = __expf(-tau * cosema[row]) * (1.0f + wgt * surprise);

    u16x8 hg = *reinterpret_cast<const u16x8*>(slots + (size_t)row * ROWSTR + 512 + lane * 8);
    float4 o0, o1;
    o0.x = bf2f(hg[0]) * gate; o0.y = bf2f(hg[1]) * gate;
    o0.z = bf2f(hg[2]) * gate; o0.w = bf2f(hg[3]) * gate;
    o1.x = bf2f(hg[4]) * gate; o1.y = bf2f(hg[5]) * gate;
    o1.z = bf2f(hg[6]) * gate; o1.w = bf2f(hg[7]) * gate;
    float* orow = reinterpret_cast<float*>(slots) + (size_t)row * DDIM + lane * 8;
    *reinterpret_cast<float4*>(orow)     = o0;
    *reinterpret_cast<float4*>(orow + 4) = o1;
}

extern "C" void kernel_launch(void* const* d_in, const int* in_sizes, int n_in,
                              void* d_out, int out_size, void* d_ws, size_t ws_size,
                              hipStream_t stream) {
    const float* x           = (const float*)d_in[0];
    // d_in[1] = logit_decay (unused by reference)
    const float* p_log_tau   = (const float*)d_in[2];
    const float* p_log_sigma = (const float*)d_in[3];
    const float* p_log_w     = (const float*)d_in[4];
    const float* ema         = (const float*)d_in[5];

    // d_out doubles as scratch: per-row 2048-B slots hold [xn bf16 | gelu bf16]
    // until finalize overwrites each slot with the fp32 output row.
    u16*   slots  = (u16*)d_out;                       // B*T*ROWSTR u16 = 33.6 MB
    float* part   = (float*)d_ws;                      // B*NT*T*4 = 2 MB
    float* cosema = (float*)((char*)d_ws + (size_t)BATCH*NT*TDIM*sizeof(float));

    prep_kernel<<<dim3(BATCH*TDIM/4), 256, 0, stream>>>(x, ema, slots, cosema);
    simmax_kernel<<<dim3(NTRI*BATCH), 256, 0, stream>>>(slots, part);
    finalize_kernel<<<dim3(BATCH*TDIM/4), 256, 0, stream>>>(
        slots, part, cosema, p_log_tau, p_log_sigma, p_log_w);
}